// Round 8
// baseline (103.333 us; speedup 1.0000x reference)
//
#include <hip/hip_runtime.h>
#include <math.h>

// ---------------------------------------------------------------------------
// FullGaussianProjector: B=1, N=512, 3 views, 224x224 out, half-res 112x112.
// memset(counter) + 3 kernels:
//   splat_fused: per-block redundant setup -> tile cull/compact (SoA f32)
//                -> 8 waves x 1/8-list chunks, each lane owns a 2x2 px quad
//                (one half-res pixel) -> LDS float4 merge -> dm.
//   blur2_stats: 2x (separable blur + where) in LDS + per-block partials;
//                last block (device atomic) reduces partials -> stats.
//   normalize:   out = (out - mean) * inv_sd   (stats preloaded)
// Closed forms:
//   sum_n nw = 0.5*(S - N*wmin)/(wmax-wmin+eps) + S/(S+eps)
//   bilinear(quadratic) = quad(Ex,Ey) - (a*Vx + c*Vy)
// NOTE (R5 lesson): a,2b,c,op must stay f32 — bf16 on the exponent path
// fails absmax through the (wmax-wmin) normalization.
// ---------------------------------------------------------------------------

__device__ __forceinline__ float wave_min(float v) {
    #pragma unroll
    for (int o = 32; o >= 1; o >>= 1) v = fminf(v, __shfl_xor(v, o));
    return v;
}

// Block: 512 threads (8 waves), tile 16x16 full-res px (8x8 quads), grid (14,14,3).
__global__ __launch_bounds__(512) void splat_fused_kernel(
    const float* __restrict__ position, const float* __restrict__ cov3d,
    const float* __restrict__ opacity, const float* __restrict__ importance,
    float* __restrict__ dm) {
    __shared__ float4 lsA[512];        // a, 2b, c, op
    __shared__ float2 lsB[512];        // gx, gy
    __shared__ float red[8 * 6];       // cross-wave min/max scratch
    __shared__ float4 pS[7][64], pMn[7][64], pMx[7][64];
    __shared__ int cnt;
    const int v = blockIdx.z;
    const int tx0 = blockIdx.x * 16, ty0 = blockIdx.y * 16;
    const int tid = threadIdx.x;
    const int lane = tid & 63, wave = tid >> 6;

    // ---------------- setup (1 gaussian per thread) ----------------
    const int n = tid;
    const float p0 = position[n * 3 + 0];
    const float p1 = position[n * 3 + 1];
    const float p2 = position[n * 3 + 2];
    const float opimp = opacity[n] * fminf(fmaxf(importance[n], 0.5f), 2.0f);

    {
        float vals[6] = {p0, -p0, p1, -p1, p2, -p2};
        #pragma unroll
        for (int k = 0; k < 6; ++k) {
            float r = wave_min(vals[k]);
            if (lane == 0) red[wave * 6 + k] = r;
        }
    }
    __syncthreads();
    float mn6[6];
    #pragma unroll
    for (int k = 0; k < 6; ++k) {
        float r = red[k];
        #pragma unroll
        for (int w = 1; w < 8; ++w) r = fminf(r, red[w * 6 + k]);
        mn6[k] = r;
    }
    const float pmn[3] = {mn6[0], mn6[2], mn6[4]};
    const float pmx[3] = {-mn6[1], -mn6[3], -mn6[5]};

    float c00 = cov3d[n * 9 + 0], c01 = cov3d[n * 9 + 1], c02 = cov3d[n * 9 + 2];
    float c10 = cov3d[n * 9 + 3], c11 = cov3d[n * 9 + 4], c12 = cov3d[n * 9 + 5];
    float c20 = cov3d[n * 9 + 6], c21 = cov3d[n * 9 + 7], c22 = cov3d[n * 9 + 8];
    for (int vv = 0; vv <= v; ++vv) {
        float s01 = 0.5f * (c01 + c10);
        float s02 = 0.5f * (c02 + c20);
        float s12 = 0.5f * (c12 + c21);
        float s00 = c00 + 1e-6f;
        float s11 = c11 + 1e-6f;
        float s22 = c22 + 1e-6f;
        float nrm = sqrtf(s00 * s00 + s11 * s11 + s22 * s22 +
                          2.0f * (s01 * s01 + s02 * s02 + s12 * s12));
        float inv = 1.0f / (nrm + 1e-6f);
        c00 = s00 * inv; c11 = s11 * inv; c22 = s22 * inv;
        c01 = s01 * inv; c10 = c01; c02 = s02 * inv; c20 = c02;
        c12 = s12 * inv; c21 = c12;
    }
    float cof00 = c11 * c22 - c12 * c12;
    float cof01 = c02 * c12 - c01 * c22;
    float cof02 = c01 * c12 - c02 * c11;
    float det = c00 * cof00 + c01 * cof01 + c02 * cof02;
    float idet = 1.0f / det;
    float i00 = cof00 * idet;
    float i01 = cof01 * idet;
    float i02 = cof02 * idet;
    float i11 = (c00 * c22 - c02 * c02) * idet;
    float i12 = (c02 * c01 - c00 * c12) * idet;
    float i22 = (c00 * c11 - c01 * c01) * idet;

    float Aa, Ab, Ac, prx, pry;
    int ix, iy;
    if (v == 0)      { Aa = i00; Ab = i01; Ac = i11; prx = p0; pry = p1; ix = 0; iy = 1; }
    else if (v == 1) { Aa = i00; Ab = i02; Ac = i22; prx = p0; pry = p2; ix = 0; iy = 2; }
    else             { Aa = i22; Ab = i12; Ac = i11; prx = p2; pry = p1; ix = 2; iy = 1; }
    Aa += 1e-10f;
    Ac += 1e-10f;

    float mnx = pmn[ix], mxx = pmx[ix], mny = pmn[iy], mxy = pmx[iy];
    float rngx = mxx - mnx + 1e-6f;
    float mnx2 = mnx - 0.5f * rngx;
    float mxx2 = mxx + 0.5f * rngx;
    rngx = mxx2 - mnx2 + 1e-6f;
    float rngy = mxy - mny + 1e-6f;
    float mny2 = mny - 0.5f * rngy;
    float mxy2 = mxy + 0.5f * rngy;
    rngy = mxy2 - mny2 + 1e-6f;
    float gx = fminf(fmaxf((prx - mnx2) / rngx * 111.0f, 0.0f), 111.0f);
    float gy = fminf(fmaxf((pry - mny2) / rngy * 111.0f, 0.0f), 111.0f);

    // ---------------- cull + compact into LDS (SoA f32) ----------------
    if (tid == 0) cnt = 0;
    __syncthreads();
    {
        const float bx0 = (float)(tx0 >> 1), bx1 = (float)((tx0 + 15) >> 1);
        const float by0 = (float)(ty0 >> 1), by1 = (float)((ty0 + 15) >> 1);
        float dx = fmaxf(fmaxf(bx0 - gx, gx - bx1), 0.0f);
        float dy = fmaxf(fmaxf(by0 - gy, gy - by1), 0.0f);
        bool pass = (dx * dx + dy * dy) < 400.01f;  // conservative superset
        unsigned long long m = __ballot(pass);
        int base = 0;
        if (lane == 0) base = atomicAdd(&cnt, __popcll(m));
        base = __shfl(base, 0);
        if (pass) {
            int slot = base + __popcll(m & ((1ull << lane) - 1ull));
            lsA[slot] = make_float4(Aa, 2.0f * Ab, Ac, opimp);
            lsB[slot] = make_float2(gx, gy);
        }
    }
    __syncthreads();
    const int len = cnt;

    // quad owned by this lane: half-res pixel (xh, yh)
    const int qx = lane & 7, qy = lane >> 3;
    const int xh = (tx0 >> 1) + qx;
    const int yh = (ty0 >> 1) + qy;

    if (len == 0) {  // uniform branch: whole block exits
        if (wave == 0) {
            #pragma unroll
            for (int py = 0; py < 2; ++py)
                #pragma unroll
                for (int px = 0; px < 2; ++px)
                    dm[(v * 224 + ty0 + 2 * qy + py) * 224 + tx0 + 2 * qx + px] = 0.0f;
        }
        return;
    }

    const int npad = (len + 15) & ~15;
    if (tid < npad - len) {  // no-op pad gaussians (mask always fails -> w=0)
        lsA[len + tid] = make_float4(1.0f, 0.0f, 1.0f, 0.0f);
        lsB[len + tid] = make_float2(1e9f, 1e9f);
    }
    __syncthreads();

    // per-parity constants (generic formula, preserves edge clamping exactly)
    float exA[2], eyA[2], VxA[2], VyA[2];
    #pragma unroll
    for (int p = 0; p < 2; ++p) {
        int xlo = xh - 1 + p; int xhi = min(xlo + 1, 111); xlo = max(xlo, 0);
        float wlo = p ? 0.75f : 0.25f, whi = 1.0f - wlo;
        exA[p] = wlo * (float)xlo + whi * (float)xhi;
        VxA[p] = wlo * whi * (float)(xhi - xlo) * (float)(xhi - xlo);
        int ylo = yh - 1 + p; int yhi2 = min(ylo + 1, 111); ylo = max(ylo, 0);
        eyA[p] = wlo * (float)ylo + whi * (float)yhi2;
        VyA[p] = wlo * whi * (float)(yhi2 - ylo) * (float)(yhi2 - ylo);
    }
    const float fxh = (float)xh, fyh = (float)yh;

    // ---------------- list chunk for this wave, quad eval ----------------
    const int chunk = npad >> 3;           // multiple of 2
    const int cbeg = wave * chunk, cend = cbeg + chunk;

    float S00 = 0.f, S01 = 0.f, S10 = 0.f, S11 = 0.f;
    float mn00 = INFINITY, mn01 = INFINITY, mn10 = INFINITY, mn11 = INFINITY;
    float mx00 = -INFINITY, mx01 = -INFINITY, mx10 = -INFINITY, mx11 = -INFINITY;

    for (int i = cbeg; i < cend; i += 2) {
        float4 gA0 = lsA[i], gA1 = lsA[i + 1];
        float2 gB0 = lsB[i], gB1 = lsB[i + 1];
        #pragma unroll
        for (int u = 0; u < 2; ++u) {
            const float4 gA = u ? gA1 : gA0;
            const float2 gB = u ? gB1 : gB0;
            const float a = gA.x, b2 = gA.y, c = gA.z, op = gA.w;
            const float xx = gB.x, yy = gB.y;
            const float dxh = fxh - xx, dyh = fyh - yy;
            const bool inside = dxh * dxh + dyh * dyh < 400.0f;
            const float dx0 = exA[0] - xx, dx1 = exA[1] - xx;
            const float dy0 = eyA[0] - yy, dy1 = eyA[1] - yy;
            const float adx0 = a * dx0, adx1 = a * dx1;
            const float bdy0 = b2 * dy0, bdy1 = b2 * dy1;
            const float cdy0 = c * dy0 * dy0, cdy1 = c * dy1 * dy1;
            const float ax0 = a * VxA[0], ax1 = a * VxA[1];
            const float cy0 = c * VyA[0], cy1 = c * VyA[1];
            #pragma unroll
            for (int py = 0; py < 2; ++py) {
                const float bdyp = py ? bdy1 : bdy0;
                const float cdyp = py ? cdy1 : cdy0;
                const float cyp  = py ? cy1 : cy0;
                #pragma unroll
                for (int px = 0; px < 2; ++px) {
                    const float dxp  = px ? dx1 : dx0;
                    const float adxp = px ? adx1 : adx0;
                    const float axp  = px ? ax1 : ax0;
                    float q = dxp * (adxp + bdyp) + cdyp;
                    float bil = -((q + axp) + cyp);
                    bil = fminf(fmaxf(bil, -20.0f), 0.0f);
                    bil = inside ? bil : -1e9f;   // exp flushes to +0
                    float w = op * __expf(bil);
                    if (py == 0 && px == 0) { S00 += w; mn00 = fminf(mn00, w); mx00 = fmaxf(mx00, w); }
                    if (py == 0 && px == 1) { S01 += w; mn01 = fminf(mn01, w); mx01 = fmaxf(mx01, w); }
                    if (py == 1 && px == 0) { S10 += w; mn10 = fminf(mn10, w); mx10 = fmaxf(mx10, w); }
                    if (py == 1 && px == 1) { S11 += w; mn11 = fminf(mn11, w); mx11 = fmaxf(mx11, w); }
                }
            }
        }
    }
    if (wave > 0) {
        pS[wave - 1][lane]  = make_float4(S00, S01, S10, S11);
        pMn[wave - 1][lane] = make_float4(mn00, mn01, mn10, mn11);
        pMx[wave - 1][lane] = make_float4(mx00, mx01, mx10, mx11);
    }
    __syncthreads();
    if (wave == 0) {
        #pragma unroll
        for (int k = 0; k < 7; ++k) {
            float4 s = pS[k][lane], m = pMn[k][lane], M = pMx[k][lane];
            S00 += s.x; S01 += s.y; S10 += s.z; S11 += s.w;
            mn00 = fminf(mn00, m.x); mn01 = fminf(mn01, m.y);
            mn10 = fminf(mn10, m.z); mn11 = fminf(mn11, m.w);
            mx00 = fmaxf(mx00, M.x); mx01 = fmaxf(mx01, M.y);
            mx10 = fmaxf(mx10, M.z); mx11 = fmaxf(mx11, M.w);
        }
        if (len < 512) {
            mn00 = fminf(mn00, 0.f); mn01 = fminf(mn01, 0.f);
            mn10 = fminf(mn10, 0.f); mn11 = fminf(mn11, 0.f);
            mx00 = fmaxf(mx00, 0.f); mx01 = fmaxf(mx01, 0.f);
            mx10 = fmaxf(mx10, 0.f); mx11 = fmaxf(mx11, 0.f);
        }
        float S4[4]  = {S00, S01, S10, S11};
        float mn4[4] = {mn00, mn01, mn10, mn11};
        float mx4[4] = {mx00, mx01, mx10, mx11};
        #pragma unroll
        for (int pp = 0; pp < 4; ++pp) {
            float S = S4[pp];
            float dmv = 0.5f * (S - 512.0f * mn4[pp]) / (mx4[pp] - mn4[pp] + 1e-6f)
                      + S / (S + 1e-6f);
            const int py = pp >> 1, px = pp & 1;
            dm[(v * 224 + ty0 + 2 * qy + py) * 224 + tx0 + 2 * qx + px] = dmv;
        }
    }
}

// Fused: d1 = where(d, blur(d)); d2 = where(d1, blur(d1)); out = d2;
// per-block partial (sum, sumsq) -> partials[bid]; LAST block reduces all
// 588 partials (double) and writes stats = (mean, 1/(sd+eps)).
__global__ __launch_bounds__(256) void blur2_stats_kernel(
    const float* __restrict__ in, float* __restrict__ out,
    float2* __restrict__ partials, int* __restrict__ counter,
    float2* __restrict__ stats) {
    __shared__ float A[28 * 29];
    __shared__ float T[28 * 29];
    __shared__ float r1[4], r2[4];
    __shared__ int isLast;
    const int v = blockIdx.z;
    const int tx0 = blockIdx.x * 16, ty0 = blockIdx.y * 16;
    const int tid = threadIdx.x;
    const float kw[7] = {0.00443305f, 0.05400558f, 0.24203623f, 0.39905030f,
                         0.24203623f, 0.05400558f, 0.00443305f};
    const float* __restrict__ chan = in + v * 224 * 224;

    for (int idx = tid; idx < 28 * 28; idx += 256) {
        int rr = idx / 28, c = idx % 28;
        int gyy = ty0 - 6 + rr, gxx = tx0 - 6 + c;
        float val = 0.0f;
        if (gyy >= 0 && gyy < 224 && gxx >= 0 && gxx < 224) val = chan[gyy * 224 + gxx];
        A[rr * 29 + c] = val;
    }
    __syncthreads();
    for (int idx = tid; idx < 22 * 28; idx += 256) {
        int rr = 3 + idx / 28, c = idx % 28;
        float s = 0.0f;
        #pragma unroll
        for (int i = 0; i < 7; ++i) s += kw[i] * A[(rr - 3 + i) * 29 + c];
        T[rr * 29 + c] = s;
    }
    __syncthreads();
    for (int idx = tid; idx < 22 * 22; idx += 256) {
        int rr = 3 + idx / 22, c = 3 + idx % 22;
        int gyy = ty0 - 6 + rr, gxx = tx0 - 6 + c;
        float s = 0.0f;
        #pragma unroll
        for (int j = 0; j < 7; ++j) s += kw[j] * T[rr * 29 + c - 3 + j];
        float ctr = A[rr * 29 + c];
        float d1 = ctr > 1e-6f ? ctr : s;
        if (gyy < 0 || gyy > 223 || gxx < 0 || gxx > 223) d1 = 0.0f;
        A[rr * 29 + c] = d1;
    }
    __syncthreads();
    for (int idx = tid; idx < 16 * 22; idx += 256) {
        int rr = 6 + idx / 22, c = 3 + idx % 22;
        float s = 0.0f;
        #pragma unroll
        for (int i = 0; i < 7; ++i) s += kw[i] * A[(rr - 3 + i) * 29 + c];
        T[rr * 29 + c] = s;
    }
    __syncthreads();
    float ls1 = 0.0f, ls2 = 0.0f;
    for (int idx = tid; idx < 16 * 16; idx += 256) {
        int rr = 6 + (idx >> 4), c = 6 + (idx & 15);
        float s = 0.0f;
        #pragma unroll
        for (int j = 0; j < 7; ++j) s += kw[j] * T[rr * 29 + c - 3 + j];
        float ctr = A[rr * 29 + c];
        float d2 = ctr > 1e-6f ? ctr : s;
        out[(v * 224 + ty0 + rr - 6) * 224 + (tx0 + c - 6)] = d2;
        ls1 += d2; ls2 += d2 * d2;
    }
    #pragma unroll
    for (int o = 32; o >= 1; o >>= 1) {
        ls1 += __shfl_xor(ls1, o);
        ls2 += __shfl_xor(ls2, o);
    }
    if ((tid & 63) == 0) { r1[tid >> 6] = ls1; r2[tid >> 6] = ls2; }
    __syncthreads();
    if (tid == 0) {
        float s1 = r1[0] + r1[1] + r1[2] + r1[3];
        float s2 = r2[0] + r2[1] + r2[2] + r2[3];
        partials[(blockIdx.z * 14 + blockIdx.y) * 14 + blockIdx.x] = make_float2(s1, s2);
        __threadfence();                      // publish partial before count
        int prev = atomicAdd(counter, 1);     // device-scope
        isLast = (prev == 588 - 1);
    }
    __syncthreads();
    if (isLast) {
        __threadfence();                      // acquire: see all partials
        double a = 0.0, b = 0.0;
        for (int i = tid; i < 588; i += 256) {
            float2 p = partials[i];
            a += (double)p.x; b += (double)p.y;
        }
        #pragma unroll
        for (int o = 32; o >= 1; o >>= 1) {
            a += __shfl_xor(a, o);
            b += __shfl_xor(b, o);
        }
        __shared__ double d1s[4], d2s[4];
        if ((tid & 63) == 0) { d1s[tid >> 6] = a; d2s[tid >> 6] = b; }
        __syncthreads();
        if (tid == 0) {
            double sa = d1s[0] + d1s[1] + d1s[2] + d1s[3];
            double sb = d2s[0] + d2s[1] + d2s[2] + d2s[3];
            const double M = 150528.0;
            double mean = sa / M;
            double var = (sb - M * mean * mean) / (M - 1.0);
            double sd = sqrt(var > 0.0 ? var : 0.0);
            stats[0] = make_float2((float)mean, 1.0f / ((float)sd + 1e-6f));
        }
    }
}

// Pure streamed normalize: out = (out - mean) * inv_sd.
__global__ __launch_bounds__(256) void normalize_kernel(
    const float2* __restrict__ stats, float* __restrict__ out) {
    const float2 s = stats[0];
    const int idx = blockIdx.x * 256 + threadIdx.x;
    if (idx < 3 * 224 * 224)
        out[idx] = (out[idx] - s.x) * s.y;
}

extern "C" void kernel_launch(void* const* d_in, const int* in_sizes, int n_in,
                              void* d_out, int out_size, void* d_ws, size_t ws_size,
                              hipStream_t stream) {
    const float* position   = (const float*)d_in[0];  // (1,512,3)
    const float* cov3d      = (const float*)d_in[1];  // (1,512,3,3)
    const float* opacity    = (const float*)d_in[2];  // (1,512)
    const float* importance = (const float*)d_in[3];  // (1,1000)
    float* out = (float*)d_out;                       // (1,3,224,224)

    float* dmA       = (float*)d_ws;                        // 150528 floats
    float2* partials = (float2*)((float*)d_ws + 150528);    // 588 float2
    float2* stats    = partials + 588;                      // 1 float2
    int* counter     = (int*)(stats + 1);                   // 1 int

    hipMemsetAsync(counter, 0, sizeof(int), stream);
    hipLaunchKernelGGL(splat_fused_kernel, dim3(14, 14, 3), dim3(512), 0, stream,
                       position, cov3d, opacity, importance, dmA);
    hipLaunchKernelGGL(blur2_stats_kernel, dim3(14, 14, 3), dim3(256), 0, stream,
                       dmA, out, partials, counter, stats);
    hipLaunchKernelGGL(normalize_kernel, dim3(588), dim3(256), 0, stream,
                       stats, out);
}

// Round 9
// 90.235 us; speedup vs baseline: 1.1452x; 1.1452x over previous
//
#include <hip/hip_runtime.h>
#include <math.h>

// ---------------------------------------------------------------------------
// FullGaussianProjector: B=1, N=512, 3 views, 224x224 out, half-res 112x112.
// 3 launches (R7 structure — R8's last-block-stats restructure regressed
// +13.5us: extra memset node + device-fence serialization; reverted):
//   splat_fused: per-block redundant setup -> tile cull/compact (SoA f32)
//                -> 8 waves x 1/8-list chunks, each lane owns a 2x2 px quad
//                (one half-res pixel) -> LDS float4 merge -> dm.
//   blur2_stats: 2x (separable blur + where) in LDS + per-block partial sums
//   normalize:   inline reduce of 588 partials -> (x-mean)/(sd+eps)
// Closed forms:
//   sum_n nw = 0.5*(S - N*wmin)/(wmax-wmin+eps) + S/(S+eps)
//   bilinear(quadratic) = quad(Ex,Ey) - (a*Vx + c*Vy)
// NOTE (R5 lesson): a,2b,c,op must stay f32 — bf16 on the exponent path
// fails absmax through the (wmax-wmin) normalization.
// ---------------------------------------------------------------------------

__device__ __forceinline__ float wave_min(float v) {
    #pragma unroll
    for (int o = 32; o >= 1; o >>= 1) v = fminf(v, __shfl_xor(v, o));
    return v;
}

// Block: 512 threads (8 waves), tile 16x16 full-res px (8x8 quads), grid (14,14,3).
__global__ __launch_bounds__(512) void splat_fused_kernel(
    const float* __restrict__ position, const float* __restrict__ cov3d,
    const float* __restrict__ opacity, const float* __restrict__ importance,
    float* __restrict__ dm) {
    __shared__ float4 lsA[512];        // a, 2b, c, op
    __shared__ float2 lsB[512];        // gx, gy
    __shared__ float red[8 * 6];       // cross-wave min/max scratch
    __shared__ float4 pS[7][64], pMn[7][64], pMx[7][64];
    __shared__ int cnt;
    const int v = blockIdx.z;
    const int tx0 = blockIdx.x * 16, ty0 = blockIdx.y * 16;
    const int tid = threadIdx.x;
    const int lane = tid & 63, wave = tid >> 6;

    // ---------------- setup (1 gaussian per thread) ----------------
    const int n = tid;
    const float p0 = position[n * 3 + 0];
    const float p1 = position[n * 3 + 1];
    const float p2 = position[n * 3 + 2];
    const float opimp = opacity[n] * fminf(fmaxf(importance[n], 0.5f), 2.0f);

    {
        float vals[6] = {p0, -p0, p1, -p1, p2, -p2};
        #pragma unroll
        for (int k = 0; k < 6; ++k) {
            float r = wave_min(vals[k]);
            if (lane == 0) red[wave * 6 + k] = r;
        }
    }
    __syncthreads();
    float mn6[6];
    #pragma unroll
    for (int k = 0; k < 6; ++k) {
        float r = red[k];
        #pragma unroll
        for (int w = 1; w < 8; ++w) r = fminf(r, red[w * 6 + k]);
        mn6[k] = r;
    }
    const float pmn[3] = {mn6[0], mn6[2], mn6[4]};
    const float pmx[3] = {-mn6[1], -mn6[3], -mn6[5]};

    float c00 = cov3d[n * 9 + 0], c01 = cov3d[n * 9 + 1], c02 = cov3d[n * 9 + 2];
    float c10 = cov3d[n * 9 + 3], c11 = cov3d[n * 9 + 4], c12 = cov3d[n * 9 + 5];
    float c20 = cov3d[n * 9 + 6], c21 = cov3d[n * 9 + 7], c22 = cov3d[n * 9 + 8];
    for (int vv = 0; vv <= v; ++vv) {
        float s01 = 0.5f * (c01 + c10);
        float s02 = 0.5f * (c02 + c20);
        float s12 = 0.5f * (c12 + c21);
        float s00 = c00 + 1e-6f;
        float s11 = c11 + 1e-6f;
        float s22 = c22 + 1e-6f;
        float nrm = sqrtf(s00 * s00 + s11 * s11 + s22 * s22 +
                          2.0f * (s01 * s01 + s02 * s02 + s12 * s12));
        float inv = 1.0f / (nrm + 1e-6f);
        c00 = s00 * inv; c11 = s11 * inv; c22 = s22 * inv;
        c01 = s01 * inv; c10 = c01; c02 = s02 * inv; c20 = c02;
        c12 = s12 * inv; c21 = c12;
    }
    float cof00 = c11 * c22 - c12 * c12;
    float cof01 = c02 * c12 - c01 * c22;
    float cof02 = c01 * c12 - c02 * c11;
    float det = c00 * cof00 + c01 * cof01 + c02 * cof02;
    float idet = 1.0f / det;
    float i00 = cof00 * idet;
    float i01 = cof01 * idet;
    float i02 = cof02 * idet;
    float i11 = (c00 * c22 - c02 * c02) * idet;
    float i12 = (c02 * c01 - c00 * c12) * idet;
    float i22 = (c00 * c11 - c01 * c01) * idet;

    float Aa, Ab, Ac, prx, pry;
    int ix, iy;
    if (v == 0)      { Aa = i00; Ab = i01; Ac = i11; prx = p0; pry = p1; ix = 0; iy = 1; }
    else if (v == 1) { Aa = i00; Ab = i02; Ac = i22; prx = p0; pry = p2; ix = 0; iy = 2; }
    else             { Aa = i22; Ab = i12; Ac = i11; prx = p2; pry = p1; ix = 2; iy = 1; }
    Aa += 1e-10f;
    Ac += 1e-10f;

    float mnx = pmn[ix], mxx = pmx[ix], mny = pmn[iy], mxy = pmx[iy];
    float rngx = mxx - mnx + 1e-6f;
    float mnx2 = mnx - 0.5f * rngx;
    float mxx2 = mxx + 0.5f * rngx;
    rngx = mxx2 - mnx2 + 1e-6f;
    float rngy = mxy - mny + 1e-6f;
    float mny2 = mny - 0.5f * rngy;
    float mxy2 = mxy + 0.5f * rngy;
    rngy = mxy2 - mny2 + 1e-6f;
    float gx = fminf(fmaxf((prx - mnx2) / rngx * 111.0f, 0.0f), 111.0f);
    float gy = fminf(fmaxf((pry - mny2) / rngy * 111.0f, 0.0f), 111.0f);

    // ---------------- cull + compact into LDS (SoA f32) ----------------
    if (tid == 0) cnt = 0;
    __syncthreads();
    {
        const float bx0 = (float)(tx0 >> 1), bx1 = (float)((tx0 + 15) >> 1);
        const float by0 = (float)(ty0 >> 1), by1 = (float)((ty0 + 15) >> 1);
        float dx = fmaxf(fmaxf(bx0 - gx, gx - bx1), 0.0f);
        float dy = fmaxf(fmaxf(by0 - gy, gy - by1), 0.0f);
        bool pass = (dx * dx + dy * dy) < 400.01f;  // conservative superset
        unsigned long long m = __ballot(pass);
        int base = 0;
        if (lane == 0) base = atomicAdd(&cnt, __popcll(m));
        base = __shfl(base, 0);
        if (pass) {
            int slot = base + __popcll(m & ((1ull << lane) - 1ull));
            lsA[slot] = make_float4(Aa, 2.0f * Ab, Ac, opimp);
            lsB[slot] = make_float2(gx, gy);
        }
    }
    __syncthreads();
    const int len = cnt;

    // quad owned by this lane: half-res pixel (xh, yh)
    const int qx = lane & 7, qy = lane >> 3;
    const int xh = (tx0 >> 1) + qx;
    const int yh = (ty0 >> 1) + qy;

    if (len == 0) {  // uniform branch: whole block exits
        if (wave == 0) {
            #pragma unroll
            for (int py = 0; py < 2; ++py)
                #pragma unroll
                for (int px = 0; px < 2; ++px)
                    dm[(v * 224 + ty0 + 2 * qy + py) * 224 + tx0 + 2 * qx + px] = 0.0f;
        }
        return;
    }

    const int npad = (len + 15) & ~15;
    if (tid < npad - len) {  // no-op pad gaussians (mask always fails -> w=0)
        lsA[len + tid] = make_float4(1.0f, 0.0f, 1.0f, 0.0f);
        lsB[len + tid] = make_float2(1e9f, 1e9f);
    }
    __syncthreads();

    // per-parity constants (generic formula, preserves edge clamping exactly)
    float exA[2], eyA[2], VxA[2], VyA[2];
    #pragma unroll
    for (int p = 0; p < 2; ++p) {
        int xlo = xh - 1 + p; int xhi = min(xlo + 1, 111); xlo = max(xlo, 0);
        float wlo = p ? 0.75f : 0.25f, whi = 1.0f - wlo;
        exA[p] = wlo * (float)xlo + whi * (float)xhi;
        VxA[p] = wlo * whi * (float)(xhi - xlo) * (float)(xhi - xlo);
        int ylo = yh - 1 + p; int yhi2 = min(ylo + 1, 111); ylo = max(ylo, 0);
        eyA[p] = wlo * (float)ylo + whi * (float)yhi2;
        VyA[p] = wlo * whi * (float)(yhi2 - ylo) * (float)(yhi2 - ylo);
    }
    const float fxh = (float)xh, fyh = (float)yh;

    // ---------------- list chunk for this wave, quad eval ----------------
    const int chunk = npad >> 3;           // multiple of 2
    const int cbeg = wave * chunk, cend = cbeg + chunk;

    float S00 = 0.f, S01 = 0.f, S10 = 0.f, S11 = 0.f;
    float mn00 = INFINITY, mn01 = INFINITY, mn10 = INFINITY, mn11 = INFINITY;
    float mx00 = -INFINITY, mx01 = -INFINITY, mx10 = -INFINITY, mx11 = -INFINITY;

    for (int i = cbeg; i < cend; i += 2) {
        float4 gA0 = lsA[i], gA1 = lsA[i + 1];
        float2 gB0 = lsB[i], gB1 = lsB[i + 1];
        #pragma unroll
        for (int u = 0; u < 2; ++u) {
            const float4 gA = u ? gA1 : gA0;
            const float2 gB = u ? gB1 : gB0;
            const float a = gA.x, b2 = gA.y, c = gA.z, op = gA.w;
            const float xx = gB.x, yy = gB.y;
            const float dxh = fxh - xx, dyh = fyh - yy;
            const bool inside = dxh * dxh + dyh * dyh < 400.0f;
            const float dx0 = exA[0] - xx, dx1 = exA[1] - xx;
            const float dy0 = eyA[0] - yy, dy1 = eyA[1] - yy;
            const float adx0 = a * dx0, adx1 = a * dx1;
            const float bdy0 = b2 * dy0, bdy1 = b2 * dy1;
            const float cdy0 = c * dy0 * dy0, cdy1 = c * dy1 * dy1;
            const float ax0 = a * VxA[0], ax1 = a * VxA[1];
            const float cy0 = c * VyA[0], cy1 = c * VyA[1];
            #pragma unroll
            for (int py = 0; py < 2; ++py) {
                const float bdyp = py ? bdy1 : bdy0;
                const float cdyp = py ? cdy1 : cdy0;
                const float cyp  = py ? cy1 : cy0;
                #pragma unroll
                for (int px = 0; px < 2; ++px) {
                    const float dxp  = px ? dx1 : dx0;
                    const float adxp = px ? adx1 : adx0;
                    const float axp  = px ? ax1 : ax0;
                    float q = dxp * (adxp + bdyp) + cdyp;
                    float bil = -((q + axp) + cyp);
                    bil = fminf(fmaxf(bil, -20.0f), 0.0f);
                    bil = inside ? bil : -1e9f;   // exp flushes to +0
                    float w = op * __expf(bil);
                    if (py == 0 && px == 0) { S00 += w; mn00 = fminf(mn00, w); mx00 = fmaxf(mx00, w); }
                    if (py == 0 && px == 1) { S01 += w; mn01 = fminf(mn01, w); mx01 = fmaxf(mx01, w); }
                    if (py == 1 && px == 0) { S10 += w; mn10 = fminf(mn10, w); mx10 = fmaxf(mx10, w); }
                    if (py == 1 && px == 1) { S11 += w; mn11 = fminf(mn11, w); mx11 = fmaxf(mx11, w); }
                }
            }
        }
    }
    if (wave > 0) {
        pS[wave - 1][lane]  = make_float4(S00, S01, S10, S11);
        pMn[wave - 1][lane] = make_float4(mn00, mn01, mn10, mn11);
        pMx[wave - 1][lane] = make_float4(mx00, mx01, mx10, mx11);
    }
    __syncthreads();
    if (wave == 0) {
        #pragma unroll
        for (int k = 0; k < 7; ++k) {
            float4 s = pS[k][lane], m = pMn[k][lane], M = pMx[k][lane];
            S00 += s.x; S01 += s.y; S10 += s.z; S11 += s.w;
            mn00 = fminf(mn00, m.x); mn01 = fminf(mn01, m.y);
            mn10 = fminf(mn10, m.z); mn11 = fminf(mn11, m.w);
            mx00 = fmaxf(mx00, M.x); mx01 = fmaxf(mx01, M.y);
            mx10 = fmaxf(mx10, M.z); mx11 = fmaxf(mx11, M.w);
        }
        if (len < 512) {
            mn00 = fminf(mn00, 0.f); mn01 = fminf(mn01, 0.f);
            mn10 = fminf(mn10, 0.f); mn11 = fminf(mn11, 0.f);
            mx00 = fmaxf(mx00, 0.f); mx01 = fmaxf(mx01, 0.f);
            mx10 = fmaxf(mx10, 0.f); mx11 = fmaxf(mx11, 0.f);
        }
        float S4[4]  = {S00, S01, S10, S11};
        float mn4[4] = {mn00, mn01, mn10, mn11};
        float mx4[4] = {mx00, mx01, mx10, mx11};
        #pragma unroll
        for (int pp = 0; pp < 4; ++pp) {
            float S = S4[pp];
            float dmv = 0.5f * (S - 512.0f * mn4[pp]) / (mx4[pp] - mn4[pp] + 1e-6f)
                      + S / (S + 1e-6f);
            const int py = pp >> 1, px = pp & 1;
            dm[(v * 224 + ty0 + 2 * qy + py) * 224 + tx0 + 2 * qx + px] = dmv;
        }
    }
}

// Fused: d1 = where(d, blur(d)); d2 = where(d1, blur(d1)); out = d2;
// per-block partial (sum, sumsq) -> partials[bid].  Tile 16x16 + halo 6.
// d1 halo outside the image is forced to 0 (exact zero-pad semantics).
__global__ __launch_bounds__(256) void blur2_stats_kernel(
    const float* __restrict__ in, float* __restrict__ out,
    float2* __restrict__ partials) {
    __shared__ float A[28 * 29];
    __shared__ float T[28 * 29];
    __shared__ float r1[4], r2[4];
    const int v = blockIdx.z;
    const int tx0 = blockIdx.x * 16, ty0 = blockIdx.y * 16;
    const int tid = threadIdx.x;
    const float kw[7] = {0.00443305f, 0.05400558f, 0.24203623f, 0.39905030f,
                         0.24203623f, 0.05400558f, 0.00443305f};
    const float* __restrict__ chan = in + v * 224 * 224;

    for (int idx = tid; idx < 28 * 28; idx += 256) {
        int rr = idx / 28, c = idx % 28;
        int gyy = ty0 - 6 + rr, gxx = tx0 - 6 + c;
        float val = 0.0f;
        if (gyy >= 0 && gyy < 224 && gxx >= 0 && gxx < 224) val = chan[gyy * 224 + gxx];
        A[rr * 29 + c] = val;
    }
    __syncthreads();
    for (int idx = tid; idx < 22 * 28; idx += 256) {
        int rr = 3 + idx / 28, c = idx % 28;
        float s = 0.0f;
        #pragma unroll
        for (int i = 0; i < 7; ++i) s += kw[i] * A[(rr - 3 + i) * 29 + c];
        T[rr * 29 + c] = s;
    }
    __syncthreads();
    for (int idx = tid; idx < 22 * 22; idx += 256) {
        int rr = 3 + idx / 22, c = 3 + idx % 22;
        int gyy = ty0 - 6 + rr, gxx = tx0 - 6 + c;
        float s = 0.0f;
        #pragma unroll
        for (int j = 0; j < 7; ++j) s += kw[j] * T[rr * 29 + c - 3 + j];
        float ctr = A[rr * 29 + c];
        float d1 = ctr > 1e-6f ? ctr : s;
        if (gyy < 0 || gyy > 223 || gxx < 0 || gxx > 223) d1 = 0.0f;
        A[rr * 29 + c] = d1;
    }
    __syncthreads();
    for (int idx = tid; idx < 16 * 22; idx += 256) {
        int rr = 6 + idx / 22, c = 3 + idx % 22;
        float s = 0.0f;
        #pragma unroll
        for (int i = 0; i < 7; ++i) s += kw[i] * A[(rr - 3 + i) * 29 + c];
        T[rr * 29 + c] = s;
    }
    __syncthreads();
    float ls1 = 0.0f, ls2 = 0.0f;
    for (int idx = tid; idx < 16 * 16; idx += 256) {
        int rr = 6 + (idx >> 4), c = 6 + (idx & 15);
        float s = 0.0f;
        #pragma unroll
        for (int j = 0; j < 7; ++j) s += kw[j] * T[rr * 29 + c - 3 + j];
        float ctr = A[rr * 29 + c];
        float d2 = ctr > 1e-6f ? ctr : s;
        out[(v * 224 + ty0 + rr - 6) * 224 + (tx0 + c - 6)] = d2;
        ls1 += d2; ls2 += d2 * d2;
    }
    #pragma unroll
    for (int o = 32; o >= 1; o >>= 1) {
        ls1 += __shfl_xor(ls1, o);
        ls2 += __shfl_xor(ls2, o);
    }
    if ((tid & 63) == 0) { r1[tid >> 6] = ls1; r2[tid >> 6] = ls2; }
    __syncthreads();
    if (tid == 0) {
        float s1 = r1[0] + r1[1] + r1[2] + r1[3];
        float s2 = r2[0] + r2[1] + r2[2] + r2[3];
        partials[(blockIdx.z * 14 + blockIdx.y) * 14 + blockIdx.x] = make_float2(s1, s2);
    }
}

// Inline reduce of 588 block partials (double), then normalize in place.
__global__ __launch_bounds__(256) void normalize_kernel(
    const float2* __restrict__ partials, float* __restrict__ out) {
    __shared__ double s1[256], s2[256];
    const int tid = threadIdx.x;
    double a = 0.0, b = 0.0;
    for (int i = tid; i < 588; i += 256) {
        float2 p = partials[i];
        a += (double)p.x; b += (double)p.y;
    }
    s1[tid] = a; s2[tid] = b;
    __syncthreads();
    for (int s = 128; s >= 1; s >>= 1) {
        if (tid < s) { s1[tid] += s1[tid + s]; s2[tid] += s2[tid + s]; }
        __syncthreads();
    }
    const double M = 150528.0;
    double mean = s1[0] / M;
    double var = (s2[0] - M * mean * mean) / (M - 1.0);
    double sd = sqrt(var > 0.0 ? var : 0.0);
    const int idx = blockIdx.x * 256 + tid;
    if (idx < 3 * 224 * 224)
        out[idx] = (out[idx] - (float)mean) / ((float)sd + 1e-6f);
}

extern "C" void kernel_launch(void* const* d_in, const int* in_sizes, int n_in,
                              void* d_out, int out_size, void* d_ws, size_t ws_size,
                              hipStream_t stream) {
    const float* position   = (const float*)d_in[0];  // (1,512,3)
    const float* cov3d      = (const float*)d_in[1];  // (1,512,3,3)
    const float* opacity    = (const float*)d_in[2];  // (1,512)
    const float* importance = (const float*)d_in[3];  // (1,1000)
    float* out = (float*)d_out;                       // (1,3,224,224)

    float* dmA       = (float*)d_ws;                  // 150528 floats
    float2* partials = (float2*)((float*)d_ws + 150528);  // 588 float2

    hipLaunchKernelGGL(splat_fused_kernel, dim3(14, 14, 3), dim3(512), 0, stream,
                       position, cov3d, opacity, importance, dmA);
    hipLaunchKernelGGL(blur2_stats_kernel, dim3(14, 14, 3), dim3(256), 0, stream,
                       dmA, out, partials);
    hipLaunchKernelGGL(normalize_kernel, dim3(588), dim3(256), 0, stream,
                       partials, out);
}